// Round 1
// baseline (1594.947 us; speedup 1.0000x reference)
//
#include <hip/hip_runtime.h>
#include <math.h>

#define NROWS 65536
#define ED 64
#define NE 2048

// workspace layout (float offsets)
#define WS_CB     0               // 2048*64 = 131072
#define WS_R      131072          // 65536 (1/softmax_denominator per row)
#define WS_INVN   196608          // 65536 (1/||z_row||)
#define WS_COUNTS 262144          // 2048
#define WS_PPART  264192          // 128 slices * 2048 = 262144
#define WS_MPART  526336          // 1024 block partials of sum(max cosine)

// output layout (float offsets): z_q_st, commit, kl, lb, cb, perplexity
#define OUT_ZQ     0
#define OUT_COMMIT 4194304
#define OUT_KL     4194305
#define OUT_LB     4194306
#define OUT_CB     4194307
#define OUT_PERP   4325379

__global__ void k_cb(const float* __restrict__ emb, float* __restrict__ cbw,
                     float* __restrict__ cbo) {
    int t = blockIdx.x * blockDim.x + threadIdx.x;
    int row = t >> 6;
    int lane = t & 63;
    if (row >= NE) return;
    float v = emb[row * ED + lane];
    float sq = v * v;
#pragma unroll
    for (int off = 32; off > 0; off >>= 1) sq += __shfl_xor(sq, off);
    float inv = 1.0f / fmaxf(sqrtf(sq), 1e-12f);
    float c = v * inv;
    cbw[row * ED + lane] = c;
    cbo[row * ED + lane] = c;
}

// Sweep 1: per-row max / argmax / sum(exp(d)) ; writes z_q rows.
// Block = 256 threads (4 waves). Block handles 64 rows; lane l of every wave
// owns row (blockIdx*64 + l); wave w covers codebook columns [w*512, w*512+512).
__launch_bounds__(256, 4)
__global__ void k_sweep1(const float* __restrict__ z, const float* __restrict__ cb,
                         float* __restrict__ zq, float* __restrict__ rws,
                         float* __restrict__ invnws, float* __restrict__ counts,
                         float* __restrict__ mpart) {
    __shared__ float m4[4][64];
    __shared__ float s4[4][64];
    __shared__ int   i4[4][64];
    __shared__ int   idxs[64];
    const int lane = threadIdx.x & 63;
    const int w = threadIdx.x >> 6;
    const int row = blockIdx.x * 64 + lane;

    float zr[ED];
    {
        const float4* zp = (const float4*)(z + (size_t)row * ED);
#pragma unroll
        for (int q = 0; q < 16; ++q) {
            float4 t = zp[q];
            zr[4*q+0] = t.x; zr[4*q+1] = t.y; zr[4*q+2] = t.z; zr[4*q+3] = t.w;
        }
    }
    float sq = 0.f;
#pragma unroll
    for (int k = 0; k < ED; ++k) sq += zr[k] * zr[k];
    const float invn = 1.0f / fmaxf(sqrtf(sq), 1e-12f);
#pragma unroll
    for (int k = 0; k < ED; ++k) zr[k] *= invn;

    float m = -2.0f; int mi = 0; float s = 0.f;
    const int j0 = w * (NE / 4);
    for (int j = j0; j < j0 + NE / 4; ++j) {
        const float* cj = cb + (size_t)j * ED;   // wave-uniform -> scalar loads
        float acc = 0.f;
#pragma unroll
        for (int k = 0; k < ED; ++k) acc = fmaf(zr[k], cj[k], acc);
        s += __expf(acc);           // d in [-1,1]: no max-subtract needed
        if (acc > m) { m = acc; mi = j; }
    }
    m4[w][lane] = m; s4[w][lane] = s; i4[w][lane] = mi;
    __syncthreads();
    if (w == 0) {
        float mm = m4[0][lane]; int ii = i4[0][lane];
        float ss = s4[0][lane];
#pragma unroll
        for (int t = 1; t < 4; ++t) {      // ascending wave order => first-occurrence argmax
            float mt = m4[t][lane];
            if (mt > mm) { mm = mt; ii = i4[t][lane]; }
            ss += s4[t][lane];
        }
        rws[row] = 1.0f / ss;
        invnws[row] = invn;
        idxs[lane] = ii;
        atomicAdd(&counts[ii], 1.0f);      // integer-valued: exact regardless of order
        float t = mm;
#pragma unroll
        for (int off = 32; off > 0; off >>= 1) t += __shfl_xor(t, off);
        if (lane == 0) mpart[blockIdx.x] = t;
    }
    __syncthreads();
    {   // write z_q = cb[idx] ; 4 threads per row, coalesced-ish 64B chunks
        const int r = threadIdx.x >> 2;
        const int q = threadIdx.x & 3;
        const int gi = idxs[r];
        const float4* src = (const float4*)(cb + (size_t)gi * ED + q * 16);
        float4* dst = (float4*)(zq + ((size_t)blockIdx.x * 64 + r) * ED + q * 16);
#pragma unroll
        for (int t = 0; t < 4; ++t) dst[t] = src[t];
    }
}

// Sweep 2: p_partial[slice][c] = sum over slice rows of exp(d)/s_i.
// Thread owns codebook column c (64 regs); z rows stream as uniform scalar loads.
__launch_bounds__(256, 4)
__global__ void k_sweep2(const float* __restrict__ z, const float* __restrict__ cb,
                         const float* __restrict__ rws, const float* __restrict__ invnws,
                         float* __restrict__ ppart) {
    const int g = blockIdx.x & 7;        // column group (8 x 256 = 2048 cols)
    const int slice = blockIdx.x >> 3;   // 128 row slices of 512 rows
    const int c = g * 256 + threadIdx.x;
    float cc[ED];
    {
        const float4* cp = (const float4*)(cb + (size_t)c * ED);
#pragma unroll
        for (int q = 0; q < 16; ++q) {
            float4 t = cp[q];
            cc[4*q+0] = t.x; cc[4*q+1] = t.y; cc[4*q+2] = t.z; cc[4*q+3] = t.w;
        }
    }
    float pacc = 0.f;
    const int i0 = slice * (NROWS / 128);
    for (int i = i0; i < i0 + NROWS / 128; ++i) {
        const float* zp = z + (size_t)i * ED;   // uniform -> scalar loads
        float acc = 0.f;
#pragma unroll
        for (int k = 0; k < ED; ++k) acc = fmaf(cc[k], zp[k], acc);
        pacc += __expf(acc * invnws[i]) * rws[i];
    }
    ppart[(size_t)slice * NE + c] = pacc;       // deterministic partials, no atomics
}

__device__ __forceinline__ float block_reduce_1024(float v, float* lds, int lane, int wid) {
#pragma unroll
    for (int off = 32; off > 0; off >>= 1) v += __shfl_xor(v, off);
    if (lane == 0) lds[wid] = v;
    __syncthreads();
    float r = 0.f;
    if (wid == 0) {
        r = (lane < 16) ? lds[lane] : 0.f;
#pragma unroll
        for (int off = 8; off > 0; off >>= 1) r += __shfl_xor(r, off);
    }
    __syncthreads();
    return r;   // valid in thread 0
}

__global__ void k_final(const float* __restrict__ counts, const float* __restrict__ ppart,
                        const float* __restrict__ mpart, float* __restrict__ out) {
    __shared__ float lds[16];
    const int tid = threadIdx.x;       // 1024 threads
    const int lane = tid & 63, wid = tid >> 6;
    float kl = 0.f, lb = 0.f, H = 0.f;
    for (int j = tid; j < NE; j += 1024) {
        float psum = 0.f;
        for (int s = 0; s < 128; ++s) psum += ppart[(size_t)s * NE + j];
        float p = psum * (1.0f / NROWS);
        float em = counts[j] * (1.0f / NROWS);
        kl += p * (logf(p) - logf(1.0f / NE));
        lb += em * p;
        H += em * logf(em + 1e-6f);
    }
    float sm = mpart[tid];             // exactly 1024 partials
    kl = block_reduce_1024(kl, lds, lane, wid);
    lb = block_reduce_1024(lb, lds, lane, wid);
    H  = block_reduce_1024(H,  lds, lane, wid);
    sm = block_reduce_1024(sm, lds, lane, wid);
    if (tid == 0) {
        out[OUT_COMMIT] = 1.25f * (1.0f - sm * (1.0f / NROWS));
        out[OUT_KL] = kl;
        out[OUT_LB] = lb;
        out[OUT_PERP] = expf(-H);
    }
}

extern "C" void kernel_launch(void* const* d_in, const int* in_sizes, int n_in,
                              void* d_out, int out_size, void* d_ws, size_t ws_size,
                              hipStream_t stream) {
    const float* z   = (const float*)d_in[0];
    const float* emb = (const float*)d_in[1];
    float* out = (float*)d_out;
    float* ws  = (float*)d_ws;

    float* cbw    = ws + WS_CB;
    float* rws    = ws + WS_R;
    float* invn   = ws + WS_INVN;
    float* counts = ws + WS_COUNTS;
    float* ppart  = ws + WS_PPART;
    float* mpart  = ws + WS_MPART;

    hipMemsetAsync(counts, 0, NE * sizeof(float), stream);
    k_cb    <<<512, 256, 0, stream>>>(emb, cbw, out + OUT_CB);
    k_sweep1<<<1024, 256, 0, stream>>>(z, cbw, out + OUT_ZQ, rws, invn, counts, mpart);
    k_sweep2<<<1024, 256, 0, stream>>>(z, cbw, rws, invn, ppart);
    k_final <<<1, 1024, 0, stream>>>(counts, ppart, mpart, out);
}

// Round 2
// 363.470 us; speedup vs baseline: 4.3881x; 4.3881x over previous
//
#include <hip/hip_runtime.h>
#include <math.h>

#define NROWS 65536
#define ED 64
#define NE 2048
#define TAU 4e-4f

typedef _Float16 f16x8 __attribute__((ext_vector_type(8)));
typedef float f32x4 __attribute__((ext_vector_type(4)));

// workspace layout (float offsets)
#define WS_CBH      0        // fp16[2048*64] = 65536 float slots
#define WS_IDX      65536    // int[65536]
#define WS_MROW     131072   // float[65536]
#define WS_PPART    196608   // float[256*2048]
#define WS_FLAGCNT  720896   // int[1] (+pad)
#define WS_FLAGLIST 720912   // int[65536]
#define WS_COUNTS   786448   // float[2048]

// output layout (float offsets): z_q_st, commit, kl, lb, cb, perplexity
#define OUT_ZQ     0
#define OUT_COMMIT 4194304
#define OUT_KL     4194305
#define OUT_LB     4194306
#define OUT_CB     4194307
#define OUT_PERP   4325379

__global__ void k_cb(const float* __restrict__ emb, _Float16* __restrict__ cbh,
                     float* __restrict__ cbo) {
    int t = blockIdx.x * blockDim.x + threadIdx.x;
    int row = t >> 6;
    int lane = t & 63;
    if (row >= NE) return;
    float v = emb[row * ED + lane];
    float sq = v * v;
#pragma unroll
    for (int off = 32; off > 0; off >>= 1) sq += __shfl_xor(sq, off);
    float c = v * (1.0f / fmaxf(sqrtf(sq), 1e-12f));
    cbo[row * ED + lane] = c;
    cbh[row * ED + lane] = (_Float16)c;
}

// Fused GEMM + softmax stats + p-partials.
// 256 blocks x 512 threads. Wave w owns cols [w*256, w*256+256), B frags resident.
// Block processes 16 row-tiles of 16 rows (grid-stride over M).
__launch_bounds__(512, 2)
__global__ void k_main(const float* __restrict__ z, const _Float16* __restrict__ cbh,
                       int* __restrict__ idxw, float* __restrict__ mrow,
                       float* __restrict__ ppart, int* __restrict__ flagcnt,
                       int* __restrict__ flaglist) {
    __shared__ float zs[16][68];          // padded: breaks 16-way bank conflict
    __shared__ float pacc[NE];
    __shared__ float st_m[8][16], st_m2[8][16], st_s[8][16];
    __shared__ int   st_i[8][16];
    __shared__ float invn[16];
    __shared__ float invs[16];

    const int tid = threadIdx.x;
    const int lane = tid & 63;
    const int w = tid >> 6;               // 0..7
    const int l15 = lane & 15;
    const int lg = lane >> 4;             // 0..3
    const int jbase = w * 256;

    for (int c = tid; c < NE; c += 512) pacc[c] = 0.f;

    // resident B fragments: cb_h[col][k], col = jbase + jf*16 + l15, k0 = ks*32 + lg*8
    f16x8 bh[16][2];
#pragma unroll
    for (int jf = 0; jf < 16; ++jf) {
        const int col = jbase + jf * 16 + l15;
#pragma unroll
        for (int ks = 0; ks < 2; ++ks) {
            const int k0 = ks * 32 + lg * 8;
            bh[jf][ks] = *(const f16x8*)(cbh + (size_t)col * ED + k0);
        }
    }

    for (int t = 0; t < 16; ++t) {
        const int rowbase = (blockIdx.x * 16 + t) * 16;
        __syncthreads();                  // protect zs/invs from previous iteration
        {   // stage 16 z rows (1024 floats) coalesced
            const float2* zp = (const float2*)(z + (size_t)rowbase * ED);
            float2 v = zp[tid];
            const int r = tid >> 5;
            const int c = (tid & 31) * 2;
            zs[r][c] = v.x; zs[r][c + 1] = v.y;
        }
        __syncthreads();
        if (w == 0) {                     // row norms: 4 lanes per row
            const int r = lane >> 2;
            const int q = lane & 3;
            float s = 0.f;
#pragma unroll
            for (int k = 0; k < 16; ++k) { float v = zs[r][q * 16 + k]; s += v * v; }
            s += __shfl_xor(s, 1); s += __shfl_xor(s, 2);
            if (q == 0) invn[r] = 1.0f / fmaxf(sqrtf(s), 1e-12f);
        }
        __syncthreads();
        // build A fragments (hi/lo fp16 split of normalized z)
        const float rn = invn[l15];
        f16x8 ah[2], al[2];
#pragma unroll
        for (int ks = 0; ks < 2; ++ks) {
            const int k0 = ks * 32 + lg * 8;
#pragma unroll
            for (int e = 0; e < 8; ++e) {
                float v = zs[l15][k0 + e] * rn;
                _Float16 h = (_Float16)v;
                ah[ks][e] = h;
                al[ks][e] = (_Float16)(v - (float)h);
            }
        }
        // MFMA: d slice for 16 rows x 256 cols
        f32x4 acc[16];
#pragma unroll
        for (int jf = 0; jf < 16; ++jf) acc[jf] = (f32x4){0.f, 0.f, 0.f, 0.f};
#pragma unroll
        for (int ks = 0; ks < 2; ++ks) {
#pragma unroll
            for (int jf = 0; jf < 16; ++jf) {
                acc[jf] = __builtin_amdgcn_mfma_f32_16x16x32_f16(ah[ks], bh[jf][ks], acc[jf], 0, 0, 0);
                acc[jf] = __builtin_amdgcn_mfma_f32_16x16x32_f16(al[ks], bh[jf][ks], acc[jf], 0, 0, 0);
            }
        }
        // per-lane stats over its 16 cols, rows = lg*4 + i (C layout: col=lane&15, row=(lane>>4)*4+i)
        float m[4], m2[4]; int mi[4];
#pragma unroll
        for (int i = 0; i < 4; ++i) { m[i] = -2.f; m2[i] = -2.f; mi[i] = 0; }
#pragma unroll
        for (int jf = 0; jf < 16; ++jf) {
            const int col = jbase + jf * 16 + l15;
#pragma unroll
            for (int i = 0; i < 4; ++i) {
                float v = acc[jf][i];
                if (v > m[i]) { m2[i] = m[i]; m[i] = v; mi[i] = col; }
                else if (v > m2[i]) m2[i] = v;
            }
        }
        // exp in place (d in [-1,1]: no max shift) + row partial sums
        float s4[4] = {0.f, 0.f, 0.f, 0.f};
#pragma unroll
        for (int jf = 0; jf < 16; ++jf)
#pragma unroll
            for (int i = 0; i < 4; ++i) {
                float e = __expf(acc[jf][i]);
                acc[jf][i] = e;
                s4[i] += e;
            }
        // reduce (m, mi, m2, s) across the 16 lanes sharing rows
#pragma unroll
        for (int d = 1; d < 16; d <<= 1) {
#pragma unroll
            for (int i = 0; i < 4; ++i) {
                float om = __shfl_xor(m[i], d);
                float om2 = __shfl_xor(m2[i], d);
                int   oi = __shfl_xor(mi[i], d);
                float os = __shfl_xor(s4[i], d);
                s4[i] += os;
                float nm2 = fmaxf(fminf(m[i], om), fmaxf(m2[i], om2));
                if (om > m[i] || (om == m[i] && oi < mi[i])) { m[i] = om; mi[i] = oi; }
                m2[i] = nm2;
            }
        }
        if (l15 == 0) {
#pragma unroll
            for (int i = 0; i < 4; ++i) {
                st_m[w][lg * 4 + i] = m[i];  st_m2[w][lg * 4 + i] = m2[i];
                st_s[w][lg * 4 + i] = s4[i]; st_i[w][lg * 4 + i] = mi[i];
            }
        }
        __syncthreads();
        if (w == 0 && lane < 16) {        // combine 8 wave slices per row
            float mm = st_m[0][lane], mm2 = st_m2[0][lane], ss = st_s[0][lane];
            int ii = st_i[0][lane];
#pragma unroll
            for (int u = 1; u < 8; ++u) {
                float om = st_m[u][lane], om2 = st_m2[u][lane];
                int oi = st_i[u][lane];
                ss += st_s[u][lane];
                float nm2 = fmaxf(fminf(mm, om), fmaxf(mm2, om2));
                if (om > mm || (om == mm && oi < ii)) { mm = om; ii = oi; }
                mm2 = nm2;
            }
            const int grow = rowbase + lane;
            idxw[grow] = ii;
            mrow[grow] = mm;
            invs[lane] = 1.0f / ss;
            if (mm - mm2 < TAU) {         // ambiguous argmax -> exact recheck
                int e = atomicAdd(flagcnt, 1);
                flaglist[e] = grow;
            }
        }
        __syncthreads();
        // column accumulation: p_col += sum_rows exp(d)/s
        const float r0 = invs[lg * 4 + 0], r1 = invs[lg * 4 + 1];
        const float r2 = invs[lg * 4 + 2], r3 = invs[lg * 4 + 3];
#pragma unroll
        for (int jf = 0; jf < 16; ++jf) {
            float v = acc[jf][0] * r0 + acc[jf][1] * r1 + acc[jf][2] * r2 + acc[jf][3] * r3;
            v += __shfl_xor(v, 16);
            v += __shfl_xor(v, 32);
            if (lg == 0) pacc[jbase + jf * 16 + l15] += v;
        }
    }
    __syncthreads();
    for (int c = tid; c < NE; c += 512)
        ppart[(size_t)blockIdx.x * NE + c] = pacc[c];
}

// Exact fp32 re-scan for flagged rows (grid-stride over flag list).
__global__ void k_recheck(const float* __restrict__ z, const float* __restrict__ cb32,
                          const int* __restrict__ flagcnt, const int* __restrict__ flaglist,
                          int* __restrict__ idxw, float* __restrict__ mrow) {
    __shared__ float zn[ED];
    __shared__ float bv[4]; __shared__ int bi[4];
    const int n = *flagcnt;
    for (int e = blockIdx.x; e < n; e += gridDim.x) {
        const int row = flaglist[e];
        __syncthreads();
        if (threadIdx.x < 64) {
            float v = z[(size_t)row * ED + threadIdx.x];
            float s = v * v;
#pragma unroll
            for (int d = 32; d > 0; d >>= 1) s += __shfl_xor(s, d);
            zn[threadIdx.x] = v * (1.0f / fmaxf(sqrtf(s), 1e-12f));
        }
        __syncthreads();
        float best = -2.f; int bidx = 0;
        for (int q = 0; q < 8; ++q) {
            const int j = q * 256 + threadIdx.x;
            const float* cj = cb32 + (size_t)j * ED;
            float acc = 0.f;
#pragma unroll
            for (int k = 0; k < ED; ++k) acc = fmaf(zn[k], cj[k], acc);
            if (acc > best) { best = acc; bidx = j; }
        }
        const int lane = threadIdx.x & 63, wv = threadIdx.x >> 6;
#pragma unroll
        for (int d = 1; d < 64; d <<= 1) {
            float ov = __shfl_xor(best, d);
            int oi = __shfl_xor(bidx, d);
            if (ov > best || (ov == best && oi < bidx)) { best = ov; bidx = oi; }
        }
        if (lane == 0) { bv[wv] = best; bi[wv] = bidx; }
        __syncthreads();
        if (threadIdx.x == 0) {
            float vB = bv[0]; int iB = bi[0];
#pragma unroll
            for (int u = 1; u < 4; ++u)
                if (bv[u] > vB || (bv[u] == vB && bi[u] < iB)) { vB = bv[u]; iB = bi[u]; }
            idxw[row] = iB; mrow[row] = vB;
        }
        __syncthreads();
    }
}

// z_q gather + exact histogram. 16 threads per row.
__global__ void k_zq(const float* __restrict__ cb32, const int* __restrict__ idxw,
                     float* __restrict__ zq, float* __restrict__ counts) {
    const int r = blockIdx.x * 16 + (threadIdx.x >> 4);
    const int q = threadIdx.x & 15;
    const int j = idxw[r];
    ((float4*)(zq + (size_t)r * ED))[q] = ((const float4*)(cb32 + (size_t)j * ED))[q];
    if (q == 0) atomicAdd(&counts[j], 1.0f);
}

__device__ __forceinline__ float block_reduce_1024(float v, float* lds, int lane, int wid) {
#pragma unroll
    for (int off = 32; off > 0; off >>= 1) v += __shfl_xor(v, off);
    if (lane == 0) lds[wid] = v;
    __syncthreads();
    float r = 0.f;
    if (wid == 0) {
        r = (lane < 16) ? lds[lane] : 0.f;
#pragma unroll
        for (int off = 8; off > 0; off >>= 1) r += __shfl_xor(r, off);
    }
    __syncthreads();
    return r;
}

__global__ void k_final(const float* __restrict__ counts, const float* __restrict__ ppart,
                        const float* __restrict__ mrow, float* __restrict__ out) {
    __shared__ float lds[16];
    const int tid = threadIdx.x;          // 1024
    const int lane = tid & 63, wid = tid >> 6;
    float sm = 0.f;
    for (int r = tid; r < NROWS; r += 1024) sm += mrow[r];
    float kl = 0.f, lb = 0.f, H = 0.f;
    const float LOGNE = logf((float)NE);
    for (int j = tid; j < NE; j += 1024) {
        float psum = 0.f;
        for (int s = 0; s < 256; ++s) psum += ppart[(size_t)s * NE + j];
        float p = psum * (1.0f / NROWS);
        float em = counts[j] * (1.0f / NROWS);
        kl += p * (logf(p) + LOGNE);
        lb += em * p;
        H += em * logf(em + 1e-6f);
    }
    sm = block_reduce_1024(sm, lds, lane, wid);
    kl = block_reduce_1024(kl, lds, lane, wid);
    lb = block_reduce_1024(lb, lds, lane, wid);
    H  = block_reduce_1024(H,  lds, lane, wid);
    if (tid == 0) {
        out[OUT_COMMIT] = 1.25f * (1.0f - sm * (1.0f / NROWS));
        out[OUT_KL] = kl;
        out[OUT_LB] = lb;
        out[OUT_PERP] = expf(-H);
    }
}

extern "C" void kernel_launch(void* const* d_in, const int* in_sizes, int n_in,
                              void* d_out, int out_size, void* d_ws, size_t ws_size,
                              hipStream_t stream) {
    const float* z   = (const float*)d_in[0];
    const float* emb = (const float*)d_in[1];
    float* out = (float*)d_out;
    float* ws  = (float*)d_ws;

    _Float16* cbh  = (_Float16*)(ws + WS_CBH);
    int* idxw      = (int*)(ws + WS_IDX);
    float* mrowp   = ws + WS_MROW;
    float* ppart   = ws + WS_PPART;
    int* flagcnt   = (int*)(ws + WS_FLAGCNT);
    int* flaglist  = (int*)(ws + WS_FLAGLIST);
    float* counts  = ws + WS_COUNTS;
    float* cb32    = out + OUT_CB;

    hipMemsetAsync(flagcnt, 0, sizeof(int), stream);
    hipMemsetAsync(counts, 0, NE * sizeof(float), stream);

    k_cb      <<<512, 256, 0, stream>>>(emb, cbh, cb32);
    k_main    <<<256, 512, 0, stream>>>(z, cbh, idxw, mrowp, ppart, flagcnt, flaglist);
    k_recheck <<<1024, 256, 0, stream>>>(z, cb32, flagcnt, flaglist, idxw, mrowp);
    k_zq      <<<4096, 256, 0, stream>>>(cb32, idxw, out + OUT_ZQ, counts);
    k_final   <<<1, 1024, 0, stream>>>(counts, ppart, mrowp, out);
}

// Round 3
// 224.345 us; speedup vs baseline: 7.1093x; 1.6201x over previous
//
#include <hip/hip_runtime.h>
#include <math.h>

#define NROWS 65536
#define ED 64
#define NE 2048
#define TAU 6e-4f

typedef _Float16 f16x8 __attribute__((ext_vector_type(8)));
typedef float f32x4 __attribute__((ext_vector_type(4)));

// workspace layout (float offsets)
#define WS_CBH      0        // fp16[2048*64] = 65536 float slots
#define WS_IDX      65536    // int[65536]
#define WS_MROW     131072   // float[65536]
#define WS_PPART    196608   // float[256*2048]
#define WS_FLAGCNT  720896   // int[1] (+pad)
#define WS_FLAGLIST 720912   // int[65536]
#define WS_COUNTS   786448   // float[2048]
#define WS_PSUM     788496   // float[2048]
#define WS_MPART    790544   // float[64]

// output layout (float offsets): z_q_st, commit, kl, lb, cb, perplexity
#define OUT_ZQ     0
#define OUT_COMMIT 4194304
#define OUT_KL     4194305
#define OUT_LB     4194306
#define OUT_CB     4194307
#define OUT_PERP   4325379

__global__ void k_cb(const float* __restrict__ emb, _Float16* __restrict__ cbh,
                     float* __restrict__ cbo) {
    int t = blockIdx.x * blockDim.x + threadIdx.x;
    int row = t >> 6;
    int lane = t & 63;
    if (row >= NE) return;
    float v = emb[row * ED + lane];
    float sq = v * v;
#pragma unroll
    for (int off = 32; off > 0; off >>= 1) sq += __shfl_xor(sq, off);
    float c = v * (1.0f / fmaxf(sqrtf(sq), 1e-12f));
    cbo[row * ED + lane] = c;
    cbh[row * ED + lane] = (_Float16)c;
}

// Transposed fused GEMM: cb = A operand, z = B operand.
// C layout: col(lane&15) = z-row, row(lane>>4)*4+i = codeword.
// 256 blocks x 512 threads; wave w owns codewords [w*256, w*256+256).
// Block processes 16 tiles of 16 z-rows.
__launch_bounds__(512, 2)
__global__ void k_main(const float* __restrict__ z, const _Float16* __restrict__ cbh,
                       int* __restrict__ idxw, float* __restrict__ mrow,
                       float* __restrict__ ppart, int* __restrict__ flagcnt,
                       int* __restrict__ flaglist) {
    __shared__ float st_m[8][16], st_m2[8][16], st_s[8][16];
    __shared__ int   st_i[8][16];
    __shared__ float invs[16];

    const int tid = threadIdx.x;
    const int lane = tid & 63;
    const int w = tid >> 6;               // 0..7
    const int l15 = lane & 15;            // z-row within tile
    const int lg = lane >> 4;             // 0..3 (k-group / codeword sub-block)
    const int cwbase = w * 256;

    f32x4 pcol[16];
#pragma unroll
    for (int jf = 0; jf < 16; ++jf) pcol[jf] = (f32x4){0.f, 0.f, 0.f, 0.f};

    const _Float16* cwp = cbh + (size_t)(cwbase + l15) * ED + lg * 8;

    for (int t = 0; t < 16; ++t) {
        const int rowbase = (blockIdx.x * 16 + t) * 16;
        // ---- load this lane's z-row slice straight from global (coalesced) ----
        const float4* zp4 = (const float4*)(z + (size_t)(rowbase + l15) * ED + lg * 8);
        const float4 za0 = zp4[0], za1 = zp4[1];     // k = lg*8 .. lg*8+7
        const float4 zb0 = zp4[8], zb1 = zp4[9];     // k = 32+lg*8 .. 32+lg*8+7
        float sq = za0.x*za0.x + za0.y*za0.y + za0.z*za0.z + za0.w*za0.w
                 + za1.x*za1.x + za1.y*za1.y + za1.z*za1.z + za1.w*za1.w
                 + zb0.x*zb0.x + zb0.y*zb0.y + zb0.z*zb0.z + zb0.w*zb0.w
                 + zb1.x*zb1.x + zb1.y*zb1.y + zb1.z*zb1.z + zb1.w*zb1.w;
        sq += __shfl_xor(sq, 16);
        sq += __shfl_xor(sq, 32);
        const float invn = 1.0f / fmaxf(sqrtf(sq), 1e-12f);
        // hi/lo fp16 split of normalized z (B fragments)
        f16x8 bh0, bl0, bh1, bl1;
        {
            const float v0[8] = {za0.x, za0.y, za0.z, za0.w, za1.x, za1.y, za1.z, za1.w};
            const float v1[8] = {zb0.x, zb0.y, zb0.z, zb0.w, zb1.x, zb1.y, zb1.z, zb1.w};
#pragma unroll
            for (int e = 0; e < 8; ++e) {
                float a = v0[e] * invn;
                _Float16 h = (_Float16)a;
                bh0[e] = h; bl0[e] = (_Float16)(a - (float)h);
                float b = v1[e] * invn;
                _Float16 g = (_Float16)b;
                bh1[e] = g; bl1[e] = (_Float16)(b - (float)g);
            }
        }
        // ---- 16 codeword tiles: mfma + branchless stats + exp ----
        f32x4 acc[16];
        float m = -2.f, m2 = -2.f, s = 0.f;
        int mi = 0;
#pragma unroll
        for (int jf = 0; jf < 16; ++jf) {
            const _Float16* ap = cwp + (size_t)jf * 16 * ED;
            const f16x8 a0 = *(const f16x8*)(ap);        // ks=0
            const f16x8 a1 = *(const f16x8*)(ap + 32);   // ks=1
            f32x4 c = (f32x4){0.f, 0.f, 0.f, 0.f};
            c = __builtin_amdgcn_mfma_f32_16x16x32_f16(a0, bh0, c, 0, 0, 0);
            c = __builtin_amdgcn_mfma_f32_16x16x32_f16(a0, bl0, c, 0, 0, 0);
            c = __builtin_amdgcn_mfma_f32_16x16x32_f16(a1, bh1, c, 0, 0, 0);
            c = __builtin_amdgcn_mfma_f32_16x16x32_f16(a1, bl1, c, 0, 0, 0);
            const int cw0 = cwbase + jf * 16 + lg * 4;
#pragma unroll
            for (int i = 0; i < 4; ++i) {
                const float v = c[i];
                m2 = fmaxf(m2, fminf(v, m));
                mi = (v > m) ? (cw0 + i) : mi;
                m  = fmaxf(v, m);
                const float e = __expf(v);
                s += e;
                c[i] = e;
            }
            acc[jf] = c;
        }
        // ---- reduce stats over the 4 lg lanes sharing this z-row ----
#pragma unroll
        for (int d = 16; d <= 32; d <<= 1) {
            const float om  = __shfl_xor(m, d);
            const float om2 = __shfl_xor(m2, d);
            const int   oi  = __shfl_xor(mi, d);
            const float os  = __shfl_xor(s, d);
            s += os;
            const float nm2 = fmaxf(fmaxf(m2, om2), fminf(m, om));
            const bool take = (om > m) || (om == m && oi < mi);
            mi = take ? oi : mi;
            m  = take ? om : m;
            m2 = nm2;
        }
        if (lane < 16) {
            st_m[w][lane] = m; st_m2[w][lane] = m2; st_s[w][lane] = s; st_i[w][lane] = mi;
        }
        __syncthreads();
        if (w == 0 && lane < 16) {        // combine 8 wave slices per row
            float mm = st_m[0][lane], mm2 = st_m2[0][lane], ss = st_s[0][lane];
            int ii = st_i[0][lane];
#pragma unroll
            for (int u = 1; u < 8; ++u) {
                const float om = st_m[u][lane], om2 = st_m2[u][lane];
                const int oi = st_i[u][lane];
                ss += st_s[u][lane];
                const float nm2 = fmaxf(fmaxf(mm2, om2), fminf(mm, om));
                const bool take = (om > mm) || (om == mm && oi < ii);
                ii = take ? oi : ii;
                mm = take ? om : mm;
                mm2 = nm2;
            }
            const int grow = rowbase + lane;
            idxw[grow] = ii;
            mrow[grow] = mm;
            invs[lane] = 1.0f / ss;
            if (mm - mm2 < TAU) {
                int e = atomicAdd(flagcnt, 1);
                flaglist[e] = grow;
            }
        }
        __syncthreads();
        const float r = invs[l15];
#pragma unroll
        for (int jf = 0; jf < 16; ++jf) {
#pragma unroll
            for (int i = 0; i < 4; ++i)
                pcol[jf][i] = fmaf(acc[jf][i], r, pcol[jf][i]);
        }
        __syncthreads();                  // invs/st reuse protection for next t
    }
    // ---- epilogue: reduce pcol over the 16 l15 lanes, store block partial ----
#pragma unroll
    for (int jf = 0; jf < 16; ++jf) {
#pragma unroll
        for (int i = 0; i < 4; ++i) {
            float v = pcol[jf][i];
            v += __shfl_xor(v, 1);
            v += __shfl_xor(v, 2);
            v += __shfl_xor(v, 4);
            v += __shfl_xor(v, 8);
            pcol[jf][i] = v;
        }
    }
    if (l15 == 0) {
        float* pp = ppart + (size_t)blockIdx.x * NE + cwbase;
#pragma unroll
        for (int jf = 0; jf < 16; ++jf) {
            float4 st;
            st.x = pcol[jf][0]; st.y = pcol[jf][1]; st.z = pcol[jf][2]; st.w = pcol[jf][3];
            *(float4*)(pp + jf * 16 + lg * 4) = st;
        }
    }
}

// Exact fp32 re-scan for flagged rows, 4 rows per codebook pass.
__launch_bounds__(256)
__global__ void k_recheck(const float* __restrict__ z, const float* __restrict__ cb32,
                          const int* __restrict__ flagcnt, const int* __restrict__ flaglist,
                          int* __restrict__ idxw, float* __restrict__ mrow) {
    __shared__ float zn[4][ED];
    __shared__ float rbv[4][4];
    __shared__ int   rbi[4][4];
    const int n = *flagcnt;
    const int tid = threadIdx.x, lane = tid & 63, wv = tid >> 6;
    for (int base = blockIdx.x * 4; base < n; base += gridDim.x * 4) {
        __syncthreads();
        {
            const int e = base + wv;
            float v = 0.f;
            if (e < n) v = z[(size_t)flaglist[e] * ED + lane];
            float sq = v * v;
#pragma unroll
            for (int d = 32; d > 0; d >>= 1) sq += __shfl_xor(sq, d);
            zn[wv][lane] = v * (1.0f / fmaxf(sqrtf(sq), 1e-12f));
        }
        __syncthreads();
        float b0 = -2.f, b1 = -2.f, b2 = -2.f, b3 = -2.f;
        int i0 = 0, i1 = 0, i2 = 0, i3 = 0;
        for (int q = 0; q < 8; ++q) {
            const int j = q * 256 + tid;
            const float* cj = cb32 + (size_t)j * ED;
            float a0 = 0.f, a1 = 0.f, a2 = 0.f, a3 = 0.f;
#pragma unroll
            for (int k = 0; k < ED; k += 4) {
                const float4 c4 = *(const float4*)(cj + k);
                a0 = fmaf(zn[0][k], c4.x, a0); a0 = fmaf(zn[0][k+1], c4.y, a0);
                a0 = fmaf(zn[0][k+2], c4.z, a0); a0 = fmaf(zn[0][k+3], c4.w, a0);
                a1 = fmaf(zn[1][k], c4.x, a1); a1 = fmaf(zn[1][k+1], c4.y, a1);
                a1 = fmaf(zn[1][k+2], c4.z, a1); a1 = fmaf(zn[1][k+3], c4.w, a1);
                a2 = fmaf(zn[2][k], c4.x, a2); a2 = fmaf(zn[2][k+1], c4.y, a2);
                a2 = fmaf(zn[2][k+2], c4.z, a2); a2 = fmaf(zn[2][k+3], c4.w, a2);
                a3 = fmaf(zn[3][k], c4.x, a3); a3 = fmaf(zn[3][k+1], c4.y, a3);
                a3 = fmaf(zn[3][k+2], c4.z, a3); a3 = fmaf(zn[3][k+3], c4.w, a3);
            }
            i0 = (a0 > b0) ? j : i0; b0 = fmaxf(a0, b0);
            i1 = (a1 > b1) ? j : i1; b1 = fmaxf(a1, b1);
            i2 = (a2 > b2) ? j : i2; b2 = fmaxf(a2, b2);
            i3 = (a3 > b3) ? j : i3; b3 = fmaxf(a3, b3);
        }
#pragma unroll
        for (int d = 1; d < 64; d <<= 1) {
            float o; int oi; bool tk;
            o = __shfl_xor(b0, d); oi = __shfl_xor(i0, d);
            tk = (o > b0) || (o == b0 && oi < i0); b0 = tk ? o : b0; i0 = tk ? oi : i0;
            o = __shfl_xor(b1, d); oi = __shfl_xor(i1, d);
            tk = (o > b1) || (o == b1 && oi < i1); b1 = tk ? o : b1; i1 = tk ? oi : i1;
            o = __shfl_xor(b2, d); oi = __shfl_xor(i2, d);
            tk = (o > b2) || (o == b2 && oi < i2); b2 = tk ? o : b2; i2 = tk ? oi : i2;
            o = __shfl_xor(b3, d); oi = __shfl_xor(i3, d);
            tk = (o > b3) || (o == b3 && oi < i3); b3 = tk ? o : b3; i3 = tk ? oi : i3;
        }
        if (lane == 0) {
            rbv[wv][0] = b0; rbi[wv][0] = i0; rbv[wv][1] = b1; rbi[wv][1] = i1;
            rbv[wv][2] = b2; rbi[wv][2] = i2; rbv[wv][3] = b3; rbi[wv][3] = i3;
        }
        __syncthreads();
        if (tid < 4) {
            const int e = base + tid;
            if (e < n) {
                float bv = rbv[0][tid]; int bi_ = rbi[0][tid];
#pragma unroll
                for (int u = 1; u < 4; ++u) {
                    const float o = rbv[u][tid]; const int oi = rbi[u][tid];
                    const bool tk = (o > bv) || (o == bv && oi < bi_);
                    bv = tk ? o : bv; bi_ = tk ? oi : bi_;
                }
                const int row = flaglist[e];
                idxw[row] = bi_;
                mrow[row] = bv;
            }
        }
    }
}

// z_q gather + exact histogram. 16 threads per row.
__global__ void k_zq(const float* __restrict__ cb32, const int* __restrict__ idxw,
                     float* __restrict__ zq, float* __restrict__ counts) {
    const int r = blockIdx.x * 16 + (threadIdx.x >> 4);
    const int q = threadIdx.x & 15;
    const int j = idxw[r];
    ((float4*)(zq + (size_t)r * ED))[q] = ((const float4*)(cb32 + (size_t)j * ED))[q];
    if (q == 0) atomicAdd(&counts[j], 1.0f);
}

// Parallel reductions: blocks 0..7 sum ppart columns; blocks 8..71 sum mrow.
__global__ void k_red(const float* __restrict__ ppart, const float* __restrict__ mrow,
                      float* __restrict__ psum, float* __restrict__ mpart) {
    const int tid = threadIdx.x;
    if (blockIdx.x < 8) {
        const int col = blockIdx.x * 256 + tid;
        float s = 0.f;
        for (int sl = 0; sl < 256; ++sl) s += ppart[(size_t)sl * NE + col];
        psum[col] = s;
    } else {
        __shared__ float lds[4];
        const int b = blockIdx.x - 8;     // 0..63
        const int r0 = b * 1024;
        float s = 0.f;
        for (int r = r0 + tid; r < r0 + 1024; r += 256) s += mrow[r];
        const int lane = tid & 63, wv = tid >> 6;
#pragma unroll
        for (int d = 32; d > 0; d >>= 1) s += __shfl_xor(s, d);
        if (lane == 0) lds[wv] = s;
        __syncthreads();
        if (tid == 0) mpart[b] = lds[0] + lds[1] + lds[2] + lds[3];
    }
}

__device__ __forceinline__ float block_reduce_1024(float v, float* lds, int lane, int wid) {
#pragma unroll
    for (int off = 32; off > 0; off >>= 1) v += __shfl_xor(v, off);
    if (lane == 0) lds[wid] = v;
    __syncthreads();
    float r = 0.f;
    if (wid == 0) {
        r = (lane < 16) ? lds[lane] : 0.f;
#pragma unroll
        for (int off = 8; off > 0; off >>= 1) r += __shfl_xor(r, off);
    }
    __syncthreads();
    return r;
}

__global__ void k_final(const float* __restrict__ counts, const float* __restrict__ psum,
                        const float* __restrict__ mpart, float* __restrict__ out) {
    __shared__ float lds[16];
    const int tid = threadIdx.x;          // 1024
    const int lane = tid & 63, wid = tid >> 6;
    float sm = (tid < 64) ? mpart[tid] : 0.f;
    float kl = 0.f, lb = 0.f, H = 0.f;
    const float LOGNE = logf((float)NE);
    for (int j = tid; j < NE; j += 1024) {
        const float p = psum[j] * (1.0f / NROWS);
        const float em = counts[j] * (1.0f / NROWS);
        kl += p * (logf(p) + LOGNE);
        lb += em * p;
        H += em * logf(em + 1e-6f);
    }
    sm = block_reduce_1024(sm, lds, lane, wid);
    kl = block_reduce_1024(kl, lds, lane, wid);
    lb = block_reduce_1024(lb, lds, lane, wid);
    H  = block_reduce_1024(H,  lds, lane, wid);
    if (tid == 0) {
        out[OUT_COMMIT] = 1.25f * (1.0f - sm * (1.0f / NROWS));
        out[OUT_KL] = kl;
        out[OUT_LB] = lb;
        out[OUT_PERP] = expf(-H);
    }
}

extern "C" void kernel_launch(void* const* d_in, const int* in_sizes, int n_in,
                              void* d_out, int out_size, void* d_ws, size_t ws_size,
                              hipStream_t stream) {
    const float* z   = (const float*)d_in[0];
    const float* emb = (const float*)d_in[1];
    float* out = (float*)d_out;
    float* ws  = (float*)d_ws;

    _Float16* cbh  = (_Float16*)(ws + WS_CBH);
    int* idxw      = (int*)(ws + WS_IDX);
    float* mrowp   = ws + WS_MROW;
    float* ppart   = ws + WS_PPART;
    int* flagcnt   = (int*)(ws + WS_FLAGCNT);
    int* flaglist  = (int*)(ws + WS_FLAGLIST);
    float* counts  = ws + WS_COUNTS;
    float* psum    = ws + WS_PSUM;
    float* mpart   = ws + WS_MPART;
    float* cb32    = out + OUT_CB;

    hipMemsetAsync(flagcnt, 0, sizeof(int), stream);
    hipMemsetAsync(counts, 0, NE * sizeof(float), stream);

    k_cb      <<<512, 256, 0, stream>>>(emb, cbh, cb32);
    k_main    <<<256, 512, 0, stream>>>(z, cbh, idxw, mrowp, ppart, flagcnt, flaglist);
    k_recheck <<<512, 256, 0, stream>>>(z, cb32, flagcnt, flaglist, idxw, mrowp);
    k_zq      <<<4096, 256, 0, stream>>>(cb32, idxw, out + OUT_ZQ, counts);
    k_red     <<<72, 256, 0, stream>>>(ppart, mrowp, psum, mpart);
    k_final   <<<1, 1024, 0, stream>>>(counts, psum, mpart, out);
}